// Round 1
// baseline (335.424 us; speedup 1.0000x reference)
//
#include <hip/hip_runtime.h>
#include <math.h>

// SlotAttention: B=32, T=4096, D=512
//   scores[b,t] = <inp[b,t,:], slot[:]>; mask t>=lens[b]; softmax over t;
//   context[b,d] = sum_t w[b,t]*inp[b,t,d]
//
// Strategy: fused single-pass online softmax, one wave per row (64 lanes x 8
// floats = 512 = D). Skip masked rows entirely (halves HBM traffic in
// expectation). Two kernels: per-chunk partials -> combine.

#define BB 32
#define TT 4096
#define DD 512

__global__ __launch_bounds__(256) void
slot_partial_kernel(const float* __restrict__ inp,
                    const int* __restrict__ lens,
                    const float* __restrict__ slot,
                    float* __restrict__ m_arr,
                    float* __restrict__ l_arr,
                    float* __restrict__ c_arr,
                    int CH, int R) {
    const int chunk = blockIdx.x;
    const int b     = blockIdx.y;
    const int tid   = threadIdx.x;
    const int wave  = tid >> 6;
    const int lane  = tid & 63;
    const int p     = b * CH + chunk;     // partial record index

    const int len = lens[b];
    const int cs  = chunk * R;
    const int ce  = min(cs + R, len);

    // slot fragment: lane covers d = lane*4..+3 and 256+lane*4..+3
    const float4 s0 = *reinterpret_cast<const float4*>(slot + lane * 4);
    const float4 s1 = *reinterpret_cast<const float4*>(slot + 256 + lane * 4);

    float  m = -INFINITY;
    float  l = 0.0f;
    float4 c0 = make_float4(0.f, 0.f, 0.f, 0.f);
    float4 c1 = make_float4(0.f, 0.f, 0.f, 0.f);

    const size_t baseB = (size_t)b * TT * DD;

    int t = cs + wave;
    if (t < ce) {
        // software pipeline: keep next row's loads in flight
        const float* rp = inp + baseB + (size_t)t * DD;
        float4 a0 = *reinterpret_cast<const float4*>(rp + lane * 4);
        float4 a1 = *reinterpret_cast<const float4*>(rp + 256 + lane * 4);
        while (t < ce) {
            const int tn = t + 4;
            float4 n0, n1;
            if (tn < ce) {
                const float* rn = inp + baseB + (size_t)tn * DD;
                n0 = *reinterpret_cast<const float4*>(rn + lane * 4);
                n1 = *reinterpret_cast<const float4*>(rn + 256 + lane * 4);
            }
            // partial dot for this lane's 8 elements
            float part = a0.x * s0.x + a0.y * s0.y + a0.z * s0.z + a0.w * s0.w
                       + a1.x * s1.x + a1.y * s1.y + a1.z * s1.z + a1.w * s1.w;
            // wave-64 butterfly reduce
            #pragma unroll
            for (int off = 32; off >= 1; off >>= 1)
                part += __shfl_xor(part, off, 64);
            const float s = part;   // uniform across wave

            // online softmax (wave-uniform branch; rarely taken after warmup)
            if (s > m) {
                const float alpha = __expf(m - s);   // first iter: exp(-inf)=0
                l *= alpha;
                c0.x *= alpha; c0.y *= alpha; c0.z *= alpha; c0.w *= alpha;
                c1.x *= alpha; c1.y *= alpha; c1.z *= alpha; c1.w *= alpha;
                m = s;
            }
            const float w = __expf(s - m);
            l += w;
            c0.x += w * a0.x; c0.y += w * a0.y; c0.z += w * a0.z; c0.w += w * a0.w;
            c1.x += w * a1.x; c1.y += w * a1.y; c1.z += w * a1.z; c1.w += w * a1.w;

            a0 = n0; a1 = n1;
            t = tn;
        }
    }

    // combine the block's 4 waves in LDS
    __shared__ float sm[4];
    __shared__ float sl[4];
    __shared__ float sc[4][DD];

    if (lane == 0) { sm[wave] = m; sl[wave] = l; }
    *reinterpret_cast<float4*>(&sc[wave][lane * 4])       = c0;
    *reinterpret_cast<float4*>(&sc[wave][256 + lane * 4]) = c1;
    __syncthreads();

    const float M = fmaxf(fmaxf(sm[0], sm[1]), fmaxf(sm[2], sm[3]));
    float aw[4];
    float L = 0.0f;
    #pragma unroll
    for (int w = 0; w < 4; ++w) {
        aw[w] = (sm[w] == -INFINITY) ? 0.0f : __expf(sm[w] - M);
        L += sl[w] * aw[w];
    }

    for (int d = tid; d < DD; d += 256) {
        const float acc = sc[0][d] * aw[0] + sc[1][d] * aw[1]
                        + sc[2][d] * aw[2] + sc[3][d] * aw[3];
        c_arr[(size_t)p * DD + d] = acc;
    }
    if (tid == 0) { m_arr[p] = M; l_arr[p] = L; }
}

__global__ __launch_bounds__(256) void
slot_combine_kernel(const float* __restrict__ m_arr,
                    const float* __restrict__ l_arr,
                    const float* __restrict__ c_arr,
                    float* __restrict__ out,
                    int CH) {
    const int b   = blockIdx.x;
    const int tid = threadIdx.x;

    __shared__ float sAlpha[64];

    // global max over this batch's chunk partials (redundant per thread; tiny)
    float M = -INFINITY;
    for (int j = 0; j < CH; ++j) M = fmaxf(M, m_arr[b * CH + j]);

    if (tid < CH) {
        const float mj = m_arr[b * CH + tid];
        sAlpha[tid] = (mj == -INFINITY) ? 0.0f : __expf(mj - M);
    }
    __syncthreads();

    float L = 0.0f;
    for (int j = 0; j < CH; ++j) L += l_arr[b * CH + j] * sAlpha[j];
    const float invL = 1.0f / L;   // lens[b] >= 1 guarantees L > 0

    for (int d = tid; d < DD; d += 256) {
        float acc = 0.0f;
        for (int j = 0; j < CH; ++j)
            acc += c_arr[((size_t)b * CH + j) * DD + d] * sAlpha[j];
        out[b * DD + d] = acc * invL;
    }
}

extern "C" void kernel_launch(void* const* d_in, const int* in_sizes, int n_in,
                              void* d_out, int out_size, void* d_ws, size_t ws_size,
                              hipStream_t stream) {
    const float* inp  = (const float*)d_in[0];
    const int*   lens = (const int*)d_in[1];
    const float* slot = (const float*)d_in[2];
    float* out = (float*)d_out;

    // pick chunks-per-batch to fit workspace: record = (m + l + c[512]) floats
    int CH = 32;
    while (CH > 1 && (size_t)BB * CH * (2 + DD) * sizeof(float) > ws_size)
        CH >>= 1;
    const int R = TT / CH;
    const int P = BB * CH;

    float* m_arr = (float*)d_ws;
    float* l_arr = m_arr + P;
    float* c_arr = l_arr + P;

    dim3 grid1(CH, BB, 1);
    slot_partial_kernel<<<grid1, 256, 0, stream>>>(inp, lens, slot,
                                                   m_arr, l_arr, c_arr, CH, R);
    slot_combine_kernel<<<BB, 256, 0, stream>>>(m_arr, l_arr, c_arr, out, CH);
}

// Round 2
// 334.663 us; speedup vs baseline: 1.0023x; 1.0023x over previous
//
#include <hip/hip_runtime.h>
#include <math.h>

// SlotAttention: B=32, T=4096, D=512
//   scores[b,t] = <inp[b,t,:], slot[:]>; mask t>=lens[b]; softmax over t;
//   context[b,d] = sum_t w[b,t]*inp[b,t,d]
//
// R1: batch rows in groups of 4 per wave so the 6-step wave-reduce chains
// overlap (4 independent shuffle chains) instead of serializing per row.
// CH=64 chunks/batch for load balance. Masked rows are never read.

#define BB 32
#define TT 4096
#define DD 512

__global__ __launch_bounds__(256) void
slot_partial_kernel(const float* __restrict__ inp,
                    const int* __restrict__ lens,
                    const float* __restrict__ slot,
                    float* __restrict__ m_arr,
                    float* __restrict__ l_arr,
                    float* __restrict__ c_arr,
                    int CH, int R, int RW) {
    const int chunk = blockIdx.x;
    const int b     = blockIdx.y;
    const int tid   = threadIdx.x;
    const int wave  = tid >> 6;
    const int lane  = tid & 63;
    const int p     = b * CH + chunk;

    const int len = lens[b];
    const int cs  = chunk * R;
    const int ws_start = cs + wave * RW;
    const int ws_end   = min(ws_start + RW, len);   // may be <= ws_start

    // slot fragment: lane covers d = lane*4..+3 and 256+lane*4..+3
    const float4 s0 = *reinterpret_cast<const float4*>(slot + lane * 4);
    const float4 s1 = *reinterpret_cast<const float4*>(slot + 256 + lane * 4);

    float  m = -INFINITY;
    float  l = 0.0f;
    float4 c0 = make_float4(0.f, 0.f, 0.f, 0.f);
    float4 c1 = make_float4(0.f, 0.f, 0.f, 0.f);

    const float* bp = inp + (size_t)b * TT * DD;

    if (ws_start < ws_end) {
        float4 a[4][2];
        // load first group (clamped rows re-read last valid row; weight 0)
        #pragma unroll
        for (int r = 0; r < 4; ++r) {
            const int t = min(ws_start + r, ws_end - 1);
            const float* rp = bp + (size_t)t * DD + lane * 4;
            a[r][0] = *reinterpret_cast<const float4*>(rp);
            a[r][1] = *reinterpret_cast<const float4*>(rp + 256);
        }
        for (int g = ws_start; g < ws_end; g += 4) {
            const int gn = g + 4;
            float4 n[4][2];
            if (gn < ws_end) {
                #pragma unroll
                for (int r = 0; r < 4; ++r) {
                    const int t = min(gn + r, ws_end - 1);
                    const float* rp = bp + (size_t)t * DD + lane * 4;
                    n[r][0] = *reinterpret_cast<const float4*>(rp);
                    n[r][1] = *reinterpret_cast<const float4*>(rp + 256);
                }
            }
            // 4 partial dots
            float sd[4];
            #pragma unroll
            for (int r = 0; r < 4; ++r) {
                sd[r] = a[r][0].x * s0.x + a[r][0].y * s0.y
                      + a[r][0].z * s0.z + a[r][0].w * s0.w
                      + a[r][1].x * s1.x + a[r][1].y * s1.y
                      + a[r][1].z * s1.z + a[r][1].w * s1.w;
            }
            // 4 interleaved butterfly reduces (independent chains)
            #pragma unroll
            for (int off = 32; off >= 1; off >>= 1) {
                #pragma unroll
                for (int r = 0; r < 4; ++r)
                    sd[r] += __shfl_xor(sd[r], off, 64);
            }
            // mask tail rows
            #pragma unroll
            for (int r = 0; r < 4; ++r)
                if (g + r >= ws_end) sd[r] = -INFINITY;

            const float gmax = fmaxf(fmaxf(sd[0], sd[1]), fmaxf(sd[2], sd[3]));
            if (gmax > m) {                       // wave-uniform, rare
                const float alpha = __expf(m - gmax);   // first time: 0
                l *= alpha;
                c0.x *= alpha; c0.y *= alpha; c0.z *= alpha; c0.w *= alpha;
                c1.x *= alpha; c1.y *= alpha; c1.z *= alpha; c1.w *= alpha;
                m = gmax;
            }
            #pragma unroll
            for (int r = 0; r < 4; ++r) {
                const float w = __expf(sd[r] - m);   // -inf rows -> 0
                l += w;
                c0.x += w * a[r][0].x; c0.y += w * a[r][0].y;
                c0.z += w * a[r][0].z; c0.w += w * a[r][0].w;
                c1.x += w * a[r][1].x; c1.y += w * a[r][1].y;
                c1.z += w * a[r][1].z; c1.w += w * a[r][1].w;
            }
            #pragma unroll
            for (int r = 0; r < 4; ++r) { a[r][0] = n[r][0]; a[r][1] = n[r][1]; }
        }
    }

    // combine the block's 4 waves in LDS
    __shared__ float sm[4];
    __shared__ float sl[4];
    __shared__ float sc[4][DD];

    if (lane == 0) { sm[wave] = m; sl[wave] = l; }
    *reinterpret_cast<float4*>(&sc[wave][lane * 4])       = c0;
    *reinterpret_cast<float4*>(&sc[wave][256 + lane * 4]) = c1;
    __syncthreads();

    const float M = fmaxf(fmaxf(sm[0], sm[1]), fmaxf(sm[2], sm[3]));
    float aw[4];
    float L = 0.0f;
    #pragma unroll
    for (int w = 0; w < 4; ++w) {
        aw[w] = (sm[w] == -INFINITY) ? 0.0f : __expf(sm[w] - M);
        L += sl[w] * aw[w];
    }

    for (int d = tid; d < DD; d += 256) {
        const float acc = sc[0][d] * aw[0] + sc[1][d] * aw[1]
                        + sc[2][d] * aw[2] + sc[3][d] * aw[3];
        c_arr[(size_t)p * DD + d] = acc;
    }
    if (tid == 0) { m_arr[p] = M; l_arr[p] = L; }
}

__global__ __launch_bounds__(256) void
slot_combine_kernel(const float* __restrict__ m_arr,
                    const float* __restrict__ l_arr,
                    const float* __restrict__ c_arr,
                    float* __restrict__ out,
                    int CH) {
    const int b   = blockIdx.x;
    const int tid = threadIdx.x;

    __shared__ float sAlpha[256];

    float M = -INFINITY;
    for (int j = 0; j < CH; ++j) M = fmaxf(M, m_arr[b * CH + j]);

    if (tid < CH) {
        const float mj = m_arr[b * CH + tid];
        sAlpha[tid] = (mj == -INFINITY) ? 0.0f : __expf(mj - M);
    }
    __syncthreads();

    float L = 0.0f;
    for (int j = 0; j < CH; ++j) L += l_arr[b * CH + j] * sAlpha[j];
    const float invL = 1.0f / L;    // lens[b] >= 1 => L > 0

    // 256 threads x float2 covers D=512
    const int d = tid * 2;
    float2 acc = make_float2(0.f, 0.f);
    for (int j = 0; j < CH; ++j) {
        const float2 v = *reinterpret_cast<const float2*>(
            c_arr + ((size_t)b * CH + j) * DD + d);
        acc.x += v.x * sAlpha[j];
        acc.y += v.y * sAlpha[j];
    }
    out[b * DD + d]     = acc.x * invL;
    out[b * DD + d + 1] = acc.y * invL;
}

extern "C" void kernel_launch(void* const* d_in, const int* in_sizes, int n_in,
                              void* d_out, int out_size, void* d_ws, size_t ws_size,
                              hipStream_t stream) {
    const float* inp  = (const float*)d_in[0];
    const int*   lens = (const int*)d_in[1];
    const float* slot = (const float*)d_in[2];
    float* out = (float*)d_out;

    // chunks-per-batch; record = (m + l + c[512]) floats
    int CH = 64;
    while (CH > 1 && (size_t)BB * CH * (2 + DD) * sizeof(float) > ws_size)
        CH >>= 1;
    const int R  = TT / CH;      // rows per chunk
    const int RW = R / 4;        // rows per wave
    const int P  = BB * CH;

    float* m_arr = (float*)d_ws;
    float* l_arr = m_arr + P;
    float* c_arr = l_arr + P;

    dim3 grid1(CH, BB, 1);
    slot_partial_kernel<<<grid1, 256, 0, stream>>>(inp, lens, slot,
                                                   m_arr, l_arr, c_arr,
                                                   CH, R, RW);
    slot_combine_kernel<<<BB, 256, 0, stream>>>(m_arr, l_arr, c_arr, out, CH);
}